// Round 1
// baseline (526.295 us; speedup 1.0000x reference)
//
#include <hip/hip_runtime.h>

// SimpleGRU scan: B=2048 seqs, T=2048 steps, H=32, O=2, fp32 backbone.
// Round-9: gate-sequential critical-path scheduling on top of R8's full-K
// 2-batch/wave mapping. R8 model (fits 533 cyc/step): LDS h round-trip ~120
// + dot issue ~195 (48 dot2 @4cyc, all 6 chains interleaved -> no gate
// finishes early) + ~90 cyc of nonlinearity chain stacked AFTER the dots.
// R9 moves the nonlinearity UNDER the dot issue and shrinks it:
//  * r-gate dots complete FIRST -> sigmoid(r) overlaps z/n dot issue.
//  * exp2 scale folded into weights/biases: r,z rows pre-scaled by -log2e,
//    n rows by 2*log2e (kills 3 chain muls).
//  * separate rcp per sigmoid (shared-rcp added 2 muls to r's path; z is
//    off critical path, r gates u = xn + r*hn).
//  * tail collapsed to ONE fma after tanh's rcp:
//      h' = (1-z)(1-2ti) + z h = m2omz*ti + ohz,
//      m2omz = 2z-2, ohz = 1 + z*(h-1); hm1 = h-1 computed in LDS-wait dead
//      time, m2omz/ohz right after z (off-path).
//  * 4 dot chains per gate (dep spacing 16cyc >= dot2 latency when one
//    gate's 16 dots issue back-to-back; 2 chains would space at 8).
// Predicted step ~380-420 cyc -> ~320-360 us.

typedef _Float16 f16x2 __attribute__((ext_vector_type(2)));

__device__ __forceinline__ float fdot2(int a, int b, float c) {
    return __builtin_amdgcn_fdot2(__builtin_bit_cast(f16x2, a),
                                  __builtin_bit_cast(f16x2, b), c, false);
}

__device__ __forceinline__ int pack_pair(float a, float b) {
    f16x2 p;
    p.x = (_Float16)a;
    p.y = (_Float16)b;
    return __builtin_bit_cast(int, p);
}

__global__ __launch_bounds__(64, 1)
void gru_scan_kernel(const float* __restrict__ x,      // [B,T]
                     const float* __restrict__ w_ih,   // [96,1]
                     const float* __restrict__ w_hh,   // [96,32]
                     const float* __restrict__ b_ih,   // [96]
                     const float* __restrict__ b_hh,   // [96]
                     const float* __restrict__ head_w, // [2,32]
                     const float* __restrict__ head_b, // [2]
                     float* __restrict__ out,          // [B,2]
                     int T)
{
    const int l = (int)threadIdx.x;
    const int g = l >> 5;   // batch slot within wave
    const int j = l & 31;   // gate/hidden row
    const int b = (int)blockIdx.x * 2 + g;

    __shared__ __align__(16) _Float16 h16[2][32];   // [group][hidden] f16
    __shared__ float hf_s[2][32];                   // fp32 h for head
    __shared__ __align__(16) float x_s[2][2][32];   // [group][buf][step]

    const float NL2E  = -1.44269504088896f;  // -log2(e): sigmoid fold
    const float P2L2E =  2.88539008177793f;  // +2*log2(e): tanh fold

    // ---- per-lane weights: rows j (r), 32+j (z), 64+j (n), full K=32,
    // PRE-SCALED so exp2 needs no chain mul. 48 int regs, asm-pinned ----
    int wR[16], wZ[16], wN[16];
    {
        const float* pR = w_hh + (     j) * 32;
        const float* pZ = w_hh + (32 + j) * 32;
        const float* pN = w_hh + (64 + j) * 32;
#pragma unroll
        for (int q = 0; q < 16; ++q) {
            wR[q] = pack_pair(NL2E  * pR[2*q], NL2E  * pR[2*q+1]);
            wZ[q] = pack_pair(NL2E  * pZ[2*q], NL2E  * pZ[2*q+1]);
            wN[q] = pack_pair(P2L2E * pN[2*q], P2L2E * pN[2*q+1]);
        }
    }
#pragma unroll
    for (int q = 0; q < 16; ++q) {
        asm volatile("" : "+v"(wR[q]), "+v"(wZ[q]), "+v"(wN[q]));
    }

    // x-path seeds, same pre-scales (all fp32)
    const float wihr = NL2E  * w_ih[j];
    const float wihz = NL2E  * w_ih[32 + j];
    const float wihn = P2L2E * w_ih[64 + j];
    const float br   = NL2E  * (b_ih[j]      + b_hh[j]);
    const float bz   = NL2E  * (b_ih[32 + j] + b_hh[32 + j]);
    const float bni  = P2L2E * b_ih[64 + j];
    const float bnh  = P2L2E * b_hh[64 + j];

    const float* xrow   = x + (size_t)b * (size_t)T;
    const int    nchunk = T >> 5;   // 32-step chunks (T=2048 -> 64)

    float h = 0.0f;
    h16[g][j]    = (_Float16)0.0f;
    x_s[g][0][j] = xrow[j];
    float xnext  = (nchunk > 1) ? xrow[32 + j] : 0.0f;
    __builtin_amdgcn_wave_barrier();

    // own group's 32 h = 64 B = 4 broadcast b128 reads (group-disjoint banks)
    const int4* hq = (const int4*)(&h16[g][0]);

    for (int c = 0; c < nchunk; ++c) {
        const int buf = c & 1;
        const float* xs = &x_s[g][buf][0];
#pragma unroll 4
        for (int s = 0; s < 32; ++s) {
            const float xv = xs[s];                  // broadcast b32
            const int4 H0 = hq[0];   // h pairs 0..3
            const int4 H1 = hq[1];   // pairs 4..7
            const int4 H2 = hq[2];   // pairs 8..11
            const int4 H3 = hq[3];   // pairs 12..15
            const float hm1 = h - 1.0f;              // off-path (LDS wait)

            // ---- r gate FIRST: its sigmoid hides under z/n dot issue ----
            float rA = fdot2(H0.x, wR[ 0], fmaf(xv, wihr, br));
            float rB = fdot2(H1.x, wR[ 4], 0.0f);
            float rC = fdot2(H2.x, wR[ 8], 0.0f);
            float rD = fdot2(H3.x, wR[12], 0.0f);
            rA = fdot2(H0.y, wR[ 1], rA); rB = fdot2(H1.y, wR[ 5], rB);
            rC = fdot2(H2.y, wR[ 9], rC); rD = fdot2(H3.y, wR[13], rD);
            rA = fdot2(H0.z, wR[ 2], rA); rB = fdot2(H1.z, wR[ 6], rB);
            rC = fdot2(H2.z, wR[10], rC); rD = fdot2(H3.z, wR[14], rD);
            rA = fdot2(H0.w, wR[ 3], rA); rB = fdot2(H1.w, wR[ 7], rB);
            rC = fdot2(H2.w, wR[11], rC); rD = fdot2(H3.w, wR[15], rD);
            const float er = __builtin_amdgcn_exp2f((rA + rB) + (rC + rD));
            const float r  = __builtin_amdgcn_rcpf(1.0f + er);

            // ---- z gate: result only needed at the very end ----
            float zA = fdot2(H0.x, wZ[ 0], fmaf(xv, wihz, bz));
            float zB = fdot2(H1.x, wZ[ 4], 0.0f);
            float zC = fdot2(H2.x, wZ[ 8], 0.0f);
            float zD = fdot2(H3.x, wZ[12], 0.0f);
            zA = fdot2(H0.y, wZ[ 1], zA); zB = fdot2(H1.y, wZ[ 5], zB);
            zC = fdot2(H2.y, wZ[ 9], zC); zD = fdot2(H3.y, wZ[13], zD);
            zA = fdot2(H0.z, wZ[ 2], zA); zB = fdot2(H1.z, wZ[ 6], zB);
            zC = fdot2(H2.z, wZ[10], zC); zD = fdot2(H3.z, wZ[14], zD);
            zA = fdot2(H0.w, wZ[ 3], zA); zB = fdot2(H1.w, wZ[ 7], zB);
            zC = fdot2(H2.w, wZ[11], zC); zD = fdot2(H3.w, wZ[15], zD);
            const float ez    = __builtin_amdgcn_exp2f((zA + zB) + (zC + zD));
            const float z     = __builtin_amdgcn_rcpf(1.0f + ez);
            const float m2omz = fmaf(2.0f, z, -2.0f);    // -(2-2z) = 2z-2
            const float ohz   = fmaf(z, hm1, 1.0f);      // 1 - z + z*h

            // ---- n gate LAST: tail = u -> exp -> rcp -> single fma ----
            float nA = fdot2(H0.x, wN[ 0], bnh);
            float nB = fdot2(H1.x, wN[ 4], 0.0f);
            float nC = fdot2(H2.x, wN[ 8], 0.0f);
            float nD = fdot2(H3.x, wN[12], 0.0f);
            nA = fdot2(H0.y, wN[ 1], nA); nB = fdot2(H1.y, wN[ 5], nB);
            nC = fdot2(H2.y, wN[ 9], nC); nD = fdot2(H3.y, wN[13], nD);
            nA = fdot2(H0.z, wN[ 2], nA); nB = fdot2(H1.z, wN[ 6], nB);
            nC = fdot2(H2.z, wN[10], nC); nD = fdot2(H3.z, wN[14], nD);
            nA = fdot2(H0.w, wN[ 3], nA); nB = fdot2(H1.w, wN[ 7], nB);
            nC = fdot2(H2.w, wN[11], nC); nD = fdot2(H3.w, wN[15], nD);
            const float np = (nA + nB) + (nC + nD);      // pre-scaled by 2log2e
            const float u  = fmaf(r, np, fmaf(xv, wihn, bni));
            const float et = __builtin_amdgcn_exp2f(u);  // = e^{2*u_orig}
            const float ti = __builtin_amdgcn_rcpf(1.0f + et);
            // h' = (1-z)*tanh + z*h = m2omz*ti + ohz  (tanh = 1 - 2*ti)
            h = fmaf(m2omz, ti, ohz);

            __builtin_amdgcn_wave_barrier();
            h16[g][j] = (_Float16)h;                 // publish for next step
            __builtin_amdgcn_wave_barrier();         // in-order DS => RAW safe
        }
        if (c + 1 < nchunk) {
            x_s[g][1 - buf][j] = xnext;              // stage next chunk
            if (c + 2 < nchunk) xnext = xrow[(c + 2) * 32 + j];
            __builtin_amdgcn_wave_barrier();
        }
    }

    // ---- head: out[b,o] = head_b[o] + sum_k h[k]*head_w[o,k] (fp32 h) ----
    hf_s[g][j] = h;
    __builtin_amdgcn_wave_barrier();
    if (l < 4) {
        const int g2 = l >> 1, o = l & 1;
        float acc = head_b[o];
        const float* hw = head_w + o * 32;
#pragma unroll
        for (int k = 0; k < 32; ++k) acc = fmaf(hf_s[g2][k], hw[k], acc);
        out[((int)blockIdx.x * 2 + g2) * 2 + o] = acc;
    }
}

extern "C" void kernel_launch(void* const* d_in, const int* in_sizes, int n_in,
                              void* d_out, int out_size, void* d_ws, size_t ws_size,
                              hipStream_t stream) {
    const float* x      = (const float*)d_in[0];
    const float* w_ih   = (const float*)d_in[1];
    const float* w_hh   = (const float*)d_in[2];
    const float* b_ih   = (const float*)d_in[3];
    const float* b_hh   = (const float*)d_in[4];
    const float* head_w = (const float*)d_in[5];
    const float* head_b = (const float*)d_in[6];
    float* out = (float*)d_out;

    const int B = out_size / 2;          // O = 2
    const int T = in_sizes[0] / B;       // x is [B,T]

    dim3 grid(B / 2), block(64);
    hipLaunchKernelGGL(gru_scan_kernel, grid, block, 0, stream,
                       x, w_ih, w_hh, b_ih, b_hh, head_w, head_b, out, T);
}

// Round 3
// 449.392 us; speedup vs baseline: 1.1711x; 1.1711x over previous
//
#include <hip/hip_runtime.h>

// SimpleGRU scan: B=2048 seqs, T=2048 steps, H=32, O=2, fp32 backbone.
// Round-10b: REGISTER-ONLY h allgather (permlane32_swap + DPP butterfly)
// replaces the LDS h round-trip (~120-150 cyc exposed/step in R8/R9).
// R10 bench died with a container failure (no compile/test error): the one
// risky construct was raw inline-asm v_permlane32_swap_b32 -- replaced here
// with the documented __builtin_amdgcn_permlane32_swap (compiler manages
// DPP hazards; r[0]=low-half broadcast, r[1]=high-half per LLVM semantics;
// init-time probe keeps weight packing robust to either orientation).
// R9 post-mortem: gate-sequential order regressed (594 vs 533 cyc/step) --
// in-order issue + 4-wide chains (16cyc spacing < ~24cyc dot2 latency) +
// add/exp2 between dot clusters blocking issue. R10 keeps R8's proven
// 6-chain interleave and R9's algebraic folds (order-neutral).
// Structure:
//  * groups remapped: batch A = lanes 0-15|32-47, B = 16-31|48-63, so the
//    cross-row h exchange is exactly permlane32_swap (hi(vdst)<->lo(src)),
//    and the rest of the allgather is DPP within rows of 16:
//    xor1 = quad_perm(0xB1), xor2 = quad_perm(0x4E),
//    xor4 = row_half_mirror(0x141) (7-k == k^7),
//    xor8 = row_mirror(0x140) (15-c == c^15).
//  * pairs are (h[c], h[c+16]) packed f16x2; butterfly scramble M[q] and
//    swap orientation folded into per-lane WEIGHT packing.
//  * chain head h -> cvt -> swap -> shl/or -> P0 ~ 20 cyc (vs ~130 LDS);
//    remaining P regs complete under the ~192-cyc dot issue.
//  * tail folds kept: weights pre-scaled by -log2e (r,z) / +2log2e (n);
//    h' = fma(2z-2, ti, 1 + z*(h-1)) single-fma tail.
// Model: issue ~267 + serial ~62 => ~330-380 cyc/step => ~290-330 us.

typedef _Float16 f16x2 __attribute__((ext_vector_type(2)));

__device__ __forceinline__ float fdot2(int a, int b, float c) {
    return __builtin_amdgcn_fdot2(__builtin_bit_cast(f16x2, a),
                                  __builtin_bit_cast(f16x2, b), c, false);
}

__device__ __forceinline__ int pack_pair(float a, float b) {
    f16x2 p;
    p.x = (_Float16)a;
    p.y = (_Float16)b;
    return __builtin_bit_cast(int, p);
}

template<int CTRL>
__device__ __forceinline__ int dppmov(int src) {
    return __builtin_amdgcn_update_dpp(0, src, CTRL, 0xF, 0xF, true);
}

__global__ __launch_bounds__(64, 1)
void gru_scan_kernel(const float* __restrict__ x,      // [B,T]
                     const float* __restrict__ w_ih,   // [96,1]
                     const float* __restrict__ w_hh,   // [96,32]
                     const float* __restrict__ b_ih,   // [96]
                     const float* __restrict__ b_hh,   // [96]
                     const float* __restrict__ head_w, // [2,32]
                     const float* __restrict__ head_b, // [2]
                     float* __restrict__ out,          // [B,2]
                     int T)
{
    const int l  = (int)threadIdx.x;
    const int gg = (l >> 4) & 1;                  // batch slot within wave
    const int m  = (l & 15) + ((l >> 5) << 4);    // local gate/hidden row 0..31
    const int b  = (int)blockIdx.x * 2 + gg;

    __shared__ float hf_s[2][32];                 // fp32 h for head
    __shared__ __align__(16) float x_s[2][2][32]; // [group][buf][step]

    // ---- orientation probe: which output of permlane32_swap holds the
    // low-half broadcast? (wave-uniform; folds into weight packing) ----
    bool lowfirst;
    {
        auto pr = __builtin_amdgcn_permlane32_swap((unsigned)l, (unsigned)l,
                                                   false, false);
        lowfirst = ((int)pr[0] == (l & 31));
    }

    const float NL2E  = -1.44269504088896f;  // -log2(e): sigmoid fold
    const float P2L2E =  2.88539008177793f;  // +2*log2(e): tanh fold

    // butterfly gather order: P[q] holds pair c0 ^ M[q]
    constexpr int M[16] = {0,1,2,3,7,6,5,4,15,14,13,12,8,9,10,11};
    const int c0 = l & 15;

    // ---- per-lane weights, packed to match the gather: pair q = columns
    // (cc, cc+16), cc = c0 ^ M[q], low/high per probe. Pre-scaled. ----
    int wR[16], wZ[16], wN[16];
    {
        const float* pR = w_hh + (     m) * 32;
        const float* pZ = w_hh + (32 + m) * 32;
        const float* pN = w_hh + (64 + m) * 32;
#pragma unroll
        for (int q = 0; q < 16; ++q) {
            const int cc  = c0 ^ M[q];
            const int clo = lowfirst ? cc      : cc + 16;
            const int chi = lowfirst ? cc + 16 : cc;
            wR[q] = pack_pair(NL2E  * pR[clo], NL2E  * pR[chi]);
            wZ[q] = pack_pair(NL2E  * pZ[clo], NL2E  * pZ[chi]);
            wN[q] = pack_pair(P2L2E * pN[clo], P2L2E * pN[chi]);
        }
    }
#pragma unroll
    for (int q = 0; q < 16; ++q) {
        asm volatile("" : "+v"(wR[q]), "+v"(wZ[q]), "+v"(wN[q]));
    }

    // x-path seeds, same pre-scales (all fp32)
    const float wihr = NL2E  * w_ih[m];
    const float wihz = NL2E  * w_ih[32 + m];
    const float wihn = P2L2E * w_ih[64 + m];
    const float br   = NL2E  * (b_ih[m]      + b_hh[m]);
    const float bz   = NL2E  * (b_ih[32 + m] + b_hh[32 + m]);
    const float bni  = P2L2E * b_ih[64 + m];
    const float bnh  = P2L2E * b_hh[64 + m];

    const float* xrow   = x + (size_t)b * (size_t)T;
    const int    nchunk = T >> 5;   // 32-step chunks (T=2048 -> 64)

    float h = 0.0f;
    x_s[gg][0][m] = xrow[m];
    float xnext  = (nchunk > 1) ? xrow[32 + m] : 0.0f;
    __builtin_amdgcn_wave_barrier();

    for (int c = 0; c < nchunk; ++c) {
        const int buf = c & 1;
        const float* xs = &x_s[gg][buf][0];
#pragma unroll 4
        for (int s = 0; s < 32; ++s) {
            const float xv  = xs[s];             // broadcast b32
            const float hm1 = h - 1.0f;          // off-path

            // ---- register allgather of h (f16): swap + DPP butterfly ----
            const unsigned hf = (unsigned)__builtin_bit_cast(unsigned short,
                                                             (_Float16)h);
            auto sw = __builtin_amdgcn_permlane32_swap(hf, hf, false, false);
            const int o0 = (int)sw[0];           // low-half bcast (per probe)
            const int o1 = (int)sw[1];           // high-half bcast
            const int P0  = (o1 << 16) | o0;     // pair c0 (hf zero-extended)
            const int P1  = dppmov<0xB1 >(P0);   // c0^1
            const int P2  = dppmov<0x4E >(P0);   // c0^2
            const int P3  = dppmov<0x4E >(P1);   // c0^3
            const int P4  = dppmov<0x141>(P0);   // c0^7
            const int P5  = dppmov<0x141>(P1);   // c0^6
            const int P6  = dppmov<0x141>(P2);   // c0^5
            const int P7  = dppmov<0x141>(P3);   // c0^4
            const int P8  = dppmov<0x140>(P0);   // c0^15
            const int P9  = dppmov<0x140>(P1);   // c0^14
            const int P10 = dppmov<0x140>(P2);   // c0^13
            const int P11 = dppmov<0x140>(P3);   // c0^12
            const int P12 = dppmov<0x140>(P4);   // c0^8
            const int P13 = dppmov<0x140>(P5);   // c0^9
            const int P14 = dppmov<0x140>(P6);   // c0^10
            const int P15 = dppmov<0x140>(P7);   // c0^11

            // ---- 6-chain interleaved dots (R8-proven 24cyc dep spacing) ----
            float rA = fdot2(P0, wR[0], fmaf(xv, wihr, br));
            float zA = fdot2(P0, wZ[0], fmaf(xv, wihz, bz));
            float nA = fdot2(P0, wN[0], bnh);
            float rB = fdot2(P8, wR[8], 0.0f);
            float zB = fdot2(P8, wZ[8], 0.0f);
            float nB = fdot2(P8, wN[8], 0.0f);
            rA = fdot2(P1, wR[1], rA); zA = fdot2(P1, wZ[1], zA); nA = fdot2(P1, wN[1], nA);
            rB = fdot2(P9, wR[9], rB); zB = fdot2(P9, wZ[9], zB); nB = fdot2(P9, wN[9], nB);
            rA = fdot2(P2, wR[2], rA); zA = fdot2(P2, wZ[2], zA); nA = fdot2(P2, wN[2], nA);
            rB = fdot2(P10, wR[10], rB); zB = fdot2(P10, wZ[10], zB); nB = fdot2(P10, wN[10], nB);
            rA = fdot2(P3, wR[3], rA); zA = fdot2(P3, wZ[3], zA); nA = fdot2(P3, wN[3], nA);
            rB = fdot2(P11, wR[11], rB); zB = fdot2(P11, wZ[11], zB); nB = fdot2(P11, wN[11], nB);
            rA = fdot2(P4, wR[4], rA); zA = fdot2(P4, wZ[4], zA); nA = fdot2(P4, wN[4], nA);
            rB = fdot2(P12, wR[12], rB); zB = fdot2(P12, wZ[12], zB); nB = fdot2(P12, wN[12], nB);
            rA = fdot2(P5, wR[5], rA); zA = fdot2(P5, wZ[5], zA); nA = fdot2(P5, wN[5], nA);
            rB = fdot2(P13, wR[13], rB); zB = fdot2(P13, wZ[13], zB); nB = fdot2(P13, wN[13], nB);
            rA = fdot2(P6, wR[6], rA); zA = fdot2(P6, wZ[6], zA); nA = fdot2(P6, wN[6], nA);
            rB = fdot2(P14, wR[14], rB); zB = fdot2(P14, wZ[14], zB); nB = fdot2(P14, wN[14], nB);
            rA = fdot2(P7, wR[7], rA); zA = fdot2(P7, wZ[7], zA); nA = fdot2(P7, wN[7], nA);
            rB = fdot2(P15, wR[15], rB); zB = fdot2(P15, wZ[15], zB); nB = fdot2(P15, wN[15], nB);

            // ---- folded tail (R9 algebra, R8 placement) ----
            const float rp = rA + rB;
            const float zp = zA + zB;
            const float np = nA + nB;
            const float er = __builtin_amdgcn_exp2f(rp);   // pre-scaled
            const float ez = __builtin_amdgcn_exp2f(zp);
            const float r  = __builtin_amdgcn_rcpf(1.0f + er);
            const float z  = __builtin_amdgcn_rcpf(1.0f + ez);
            const float m2omz = fmaf(2.0f, z, -2.0f);      // 2z-2
            const float ohz   = fmaf(z, hm1, 1.0f);        // 1 - z + z*h
            const float u  = fmaf(r, np, fmaf(xv, wihn, bni));
            const float et = __builtin_amdgcn_exp2f(u);    // e^{2*u_orig}
            const float ti = __builtin_amdgcn_rcpf(1.0f + et);
            h = fmaf(m2omz, ti, ohz);    // (1-z)*tanh + z*h, tanh = 1-2ti
        }
        if (c + 1 < nchunk) {
            x_s[gg][1 - buf][m] = xnext;             // stage next chunk
            if (c + 2 < nchunk) xnext = xrow[(c + 2) * 32 + m];
            __builtin_amdgcn_wave_barrier();
        }
    }

    // ---- head: out[b,o] = head_b[o] + sum_k h[k]*head_w[o,k] (fp32 h) ----
    hf_s[gg][m] = h;
    __builtin_amdgcn_wave_barrier();
    if (l < 4) {
        const int g2 = l >> 1, o = l & 1;
        float acc = head_b[o];
        const float* hw = head_w + o * 32;
#pragma unroll
        for (int k = 0; k < 32; ++k) acc = fmaf(hf_s[g2][k], hw[k], acc);
        out[((int)blockIdx.x * 2 + g2) * 2 + o] = acc;
    }
}

extern "C" void kernel_launch(void* const* d_in, const int* in_sizes, int n_in,
                              void* d_out, int out_size, void* d_ws, size_t ws_size,
                              hipStream_t stream) {
    const float* x      = (const float*)d_in[0];
    const float* w_ih   = (const float*)d_in[1];
    const float* w_hh   = (const float*)d_in[2];
    const float* b_ih   = (const float*)d_in[3];
    const float* b_hh   = (const float*)d_in[4];
    const float* head_w = (const float*)d_in[5];
    const float* head_b = (const float*)d_in[6];
    float* out = (float*)d_out;

    const int B = out_size / 2;          // O = 2
    const int T = in_sizes[0] / B;       // x is [B,T]

    dim3 grid(B / 2), block(64);
    hipLaunchKernelGGL(gru_scan_kernel, grid, block, 0, stream,
                       x, w_ih, w_hh, b_ih, b_hh, head_w, head_b, out, T);
}